// Round 1
// baseline (473.470 us; speedup 1.0000x reference)
//
#include <hip/hip_runtime.h>
#include <hip/hip_bf16.h>
#include <math.h>

// Problem constants: B=4, T=2048, C=1024, H=16, D=64
#define B_   4
#define T_   2048
#define C_   1024
#define H_   16
#define D_   64
#define M_   (B_*T_)   // 8192 rows
#define N3   (3*C_)    // 3072
#define KDIM C_        // 1024

typedef __attribute__((ext_vector_type(8))) short bf16x8;   // 8 bf16 = 4 VGPR (MFMA A/B frag)
typedef __attribute__((ext_vector_type(4))) float f32x4;    // MFMA C/D frag

#define MFMA16(a,b,c) __builtin_amdgcn_mfma_f32_16x16x32_bf16(a,b,c,0,0,0)

__device__ __forceinline__ unsigned short f2bf(float f) {
  union { float f; unsigned u; } a; a.f = f;
  unsigned r = a.u + 0x7fffu + ((a.u >> 16) & 1u);   // RNE (inputs are finite)
  return (unsigned short)(r >> 16);
}

__device__ __forceinline__ void gload16(const void* g, void* l) {
  // async global->LDS, 16B per lane; LDS dest = wave-uniform base + lane*16
  __builtin_amdgcn_global_load_lds(
      (const __attribute__((address_space(1))) void*)g,
      (__attribute__((address_space(3))) void*)l, 16, 0, 0);
}

// ---------------- cast x (f32 -> bf16), 4 elems/thread ----------------
__global__ void cast_f32_bf16(const float* __restrict__ in,
                              unsigned short* __restrict__ out, int n) {
  int i = (blockIdx.x * 256 + threadIdx.x) * 4;
  if (i >= n) return;
  float4 v = *(const float4*)(in + i);
  ushort4 o;
  o.x = f2bf(v.x); o.y = f2bf(v.y); o.z = f2bf(v.z); o.w = f2bf(v.w);
  *(ushort4*)(out + i) = o;
}

// -------- transpose + cast: in[R][Ncols] f32 -> out[Ncols][R] bf16 --------
__global__ void transpose_cast(const float* __restrict__ in,
                               unsigned short* __restrict__ out,
                               int R, int Ncols) {
  __shared__ float tile[32][33];           // +1 pad: no bank conflicts
  int bc = blockIdx.x * 32;                // col base (Ncols dim)
  int br = blockIdx.y * 32;                // row base (R dim)
  int tx = threadIdx.x, ty = threadIdx.y;  // 32 x 8
  #pragma unroll
  for (int i = ty; i < 32; i += 8)
    tile[i][tx] = in[(size_t)(br + i) * Ncols + bc + tx];
  __syncthreads();
  #pragma unroll
  for (int i = ty; i < 32; i += 8)
    out[(size_t)(bc + i) * R + br + tx] = f2bf(tile[tx][i]);
}

// ---------------- 128x128x64 bf16 MFMA GEMM, Bt = B transposed [N][K] ------
// MODE 0: QKV epilogue -> q (scaled 0.125), k, vT scatter (bf16)
// MODE 1: plain f32 C write (proj)
template<int MODE>
__global__ __launch_bounds__(256)
void gemm128(const unsigned short* __restrict__ A,    // [M][K] bf16
             const unsigned short* __restrict__ Bt,   // [N][K] bf16
             unsigned short* __restrict__ qo,
             unsigned short* __restrict__ ko,
             unsigned short* __restrict__ vto,
             float* __restrict__ outf) {
  __shared__ short Asl[128 * 64];   // [m 128][k 64], 16KB
  __shared__ short Bsl[128 * 64];   // [n 128][k 64], 16KB
  const int tid  = threadIdx.x;
  const int wid  = tid >> 6, lane = tid & 63;
  const int l15  = lane & 15, l4 = lane >> 4;
  const int tm   = blockIdx.y * 128;
  const int tn   = blockIdx.x * 128;
  const int wm   = (wid >> 1) * 64, wn = (wid & 1) * 64;

  f32x4 acc[4][4] = {};

  const int stoff = wid * 1024 + lane * 16;   // this thread's byte slot per round

  for (int kt = 0; kt < KDIM; kt += 64) {
    __syncthreads();   // previous compute done before overwriting LDS
    #pragma unroll
    for (int ro = 0; ro < 4; ++ro) {
      int off = ro * 4096 + stoff;
      int row = off >> 7;              // 128B per LDS row (64 bf16)
      int ce  = (off & 127) >> 1;      // elem within row
      gload16(A  + (size_t)(tm + row) * KDIM + kt + ce,
              (char*)Asl + ro * 4096 + wid * 1024);
      gload16(Bt + (size_t)(tn + row) * KDIM + kt + ce,
              (char*)Bsl + ro * 4096 + wid * 1024);
    }
    __syncthreads();   // compiler drains vmcnt before s_barrier -> tiles ready

    #pragma unroll
    for (int ks = 0; ks < 2; ++ks) {
      bf16x8 af[4], bfr[4];
      #pragma unroll
      for (int i = 0; i < 4; ++i) {
        af[i]  = *(const bf16x8*)&Asl[(wm + i*16 + l15) * 64 + ks*32 + l4*8];
        bfr[i] = *(const bf16x8*)&Bsl[(wn + i*16 + l15) * 64 + ks*32 + l4*8];
      }
      #pragma unroll
      for (int mi = 0; mi < 4; ++mi)
        #pragma unroll
        for (int ni = 0; ni < 4; ++ni)
          acc[mi][ni] = MFMA16(af[mi], bfr[ni], acc[mi][ni]);
    }
  }

  // epilogue: D[row][col], col = lane&15, row = (lane>>4)*4 + r  [measured m89/m91]
  #pragma unroll
  for (int mi = 0; mi < 4; ++mi) {
    #pragma unroll
    for (int ni = 0; ni < 4; ++ni) {
      #pragma unroll
      for (int r = 0; r < 4; ++r) {
        int m = tm + wm + mi*16 + l4*4 + r;
        int n = tn + wn + ni*16 + l15;
        float val = acc[mi][ni][r];
        if (MODE == 0) {
          int b = m >> 11, t = m & (T_ - 1);
          int which = n >> 10, n1 = n & (C_ - 1);
          int h = n1 >> 6, d = n1 & 63;
          size_t bh = (size_t)(b * H_ + h);
          if (which == 0)      qo[(bh * T_ + t) * D_ + d] = f2bf(val * 0.125f); // fold 1/sqrt(D)
          else if (which == 1) ko[(bh * T_ + t) * D_ + d] = f2bf(val);
          else                 vto[(bh * D_ + d) * T_ + t] = f2bf(val);          // V transposed
        } else {
          outf[(size_t)m * C_ + n] = val;
        }
      }
    }
  }
}

// ---------------- causal flash attention -----------------------------------
// grid (64 bh, 32 qtiles rev), block 256 = 4 independent waves, 16 q-rows/wave
__global__ __launch_bounds__(256)
void attn64(const unsigned short* __restrict__ Q,    // [BH][T][D], pre-scaled
            const unsigned short* __restrict__ K,    // [BH][T][D]
            const unsigned short* __restrict__ Vt,   // [BH][D][T]
            unsigned short* __restrict__ Y) {        // [B][T][C] bf16
  __shared__ short P_lds[4][16 * 64];   // per-wave P buffer
  const int bh  = blockIdx.x;
  const int qt  = (int)gridDim.y - 1 - (int)blockIdx.y;  // heavy tiles first
  const int tid = threadIdx.x, wid = tid >> 6, lane = tid & 63;
  const int l15 = lane & 15, l4 = lane >> 4;
  const int q0  = qt * 64 + wid * 16;                    // wave's q rows
  const int b   = bh >> 4, h = bh & 15;

  const unsigned short* Qp = Q  + (size_t)bh * T_ * D_;
  const unsigned short* Kp = K  + (size_t)bh * T_ * D_;
  const unsigned short* Vp = Vt + (size_t)bh * D_ * T_;

  bf16x8 qf[2];
  #pragma unroll
  for (int c = 0; c < 2; ++c)
    qf[c] = *(const bf16x8*)&Qp[(q0 + l15) * D_ + c*32 + l4*8];

  f32x4 yacc[4] = {};                                    // [d-subtile]
  float mrow[4] = {-INFINITY, -INFINITY, -INFINITY, -INFINITY};
  float lrow[4] = {0.f, 0.f, 0.f, 0.f};
  short* pl = &P_lds[wid][0];

  for (int kt = 0; kt <= qt; ++kt) {
    const int k0 = kt * 64;
    // S = Q K^T  (S frag: col=key=lane&15, row=q=(lane>>4)*4+r)
    f32x4 s[4];
    #pragma unroll
    for (int ksub = 0; ksub < 4; ++ksub) {
      f32x4 a = {0.f, 0.f, 0.f, 0.f};
      #pragma unroll
      for (int c = 0; c < 2; ++c) {
        bf16x8 kf = *(const bf16x8*)&Kp[(size_t)(k0 + ksub*16 + l15) * D_ + c*32 + l4*8];
        a = MFMA16(qf[c], kf, a);
      }
      s[ksub] = a;
    }
    if (kt == qt) {   // diagonal tile: mask k > q
      #pragma unroll
      for (int ksub = 0; ksub < 4; ++ksub)
        #pragma unroll
        for (int r = 0; r < 4; ++r)
          if (k0 + ksub*16 + l15 > q0 + l4*4 + r) s[ksub][r] = -INFINITY;
    }
    // online softmax: wave-parallel row reduce over 16-lane groups
    float scale[4];
    #pragma unroll
    for (int r = 0; r < 4; ++r) {
      float v = fmaxf(fmaxf(s[0][r], s[1][r]), fmaxf(s[2][r], s[3][r]));
      #pragma unroll
      for (int off = 1; off < 16; off <<= 1)
        v = fmaxf(v, __shfl_xor(v, off, 64));
      float mn = fmaxf(mrow[r], v);
      scale[r] = __expf(mrow[r] - mn);
      mrow[r] = mn;
    }
    float rsum[4] = {0.f, 0.f, 0.f, 0.f};
    #pragma unroll
    for (int ksub = 0; ksub < 4; ++ksub)
      #pragma unroll
      for (int r = 0; r < 4; ++r) {
        float p = __expf(s[ksub][r] - mrow[r]);
        s[ksub][r] = p;
        rsum[r] += p;
      }
    #pragma unroll
    for (int r = 0; r < 4; ++r) {
      #pragma unroll
      for (int off = 1; off < 16; off <<= 1)
        rsum[r] += __shfl_xor(rsum[r], off, 64);
      lrow[r] = lrow[r] * scale[r] + rsum[r];
    }
    #pragma unroll
    for (int di = 0; di < 4; ++di)
      #pragma unroll
      for (int r = 0; r < 4; ++r)
        yacc[di][r] *= scale[r];

    // P: D-frag layout -> A-frag layout via per-wave LDS (waves independent)
    asm volatile("s_waitcnt lgkmcnt(0)" ::: "memory");  // prior reads done
    #pragma unroll
    for (int ksub = 0; ksub < 4; ++ksub)
      #pragma unroll
      for (int r = 0; r < 4; ++r)
        pl[(l4*4 + r) * 64 + ksub*16 + l15] = (short)f2bf(s[ksub][r]);
    asm volatile("s_waitcnt lgkmcnt(0)" ::: "memory");  // writes visible
    __builtin_amdgcn_sched_barrier(0);
    bf16x8 pf[2];
    #pragma unroll
    for (int c = 0; c < 2; ++c)
      pf[c] = *(const bf16x8*)&pl[l15 * 64 + c*32 + l4*8];

    // Y += P V   (V frags contiguous from Vt layout)
    #pragma unroll
    for (int di = 0; di < 4; ++di) {
      #pragma unroll
      for (int c = 0; c < 2; ++c) {
        bf16x8 vf = *(const bf16x8*)&Vp[(size_t)(di*16 + l15) * T_ + k0 + c*32 + l4*8];
        yacc[di] = MFMA16(pf[c], vf, yacc[di]);
      }
    }
  }

  #pragma unroll
  for (int di = 0; di < 4; ++di) {
    #pragma unroll
    for (int r = 0; r < 4; ++r) {
      int t = q0 + l4*4 + r;
      int d = di*16 + l15;
      Y[((size_t)b * T_ + t) * C_ + h * D_ + d] = f2bf(yacc[di][r] / lrow[r]);
    }
  }
}

// ---------------------------------------------------------------------------
extern "C" void kernel_launch(void* const* d_in, const int* in_sizes, int n_in,
                              void* d_out, int out_size, void* d_ws, size_t ws_size,
                              hipStream_t stream) {
  const float* x      = (const float*)d_in[0];
  const float* w_attn = (const float*)d_in[1];
  const float* w_proj = (const float*)d_in[2];
  float* out = (float*)d_out;

  char* ws = (char*)d_ws;
  size_t off = 0;
  auto alloc = [&](size_t bytes) {
    char* p = ws + off; off += (bytes + 255) & ~(size_t)255; return p;
  };
  unsigned short* xb  = (unsigned short*)alloc((size_t)M_ * C_ * 2);  // x bf16
  unsigned short* wat = (unsigned short*)alloc((size_t)N3 * KDIM * 2);// w_attn^T bf16
  unsigned short* wpt = (unsigned short*)alloc((size_t)C_ * C_ * 2);  // w_proj^T bf16
  unsigned short* qb  = (unsigned short*)alloc((size_t)M_ * C_ * 2);  // Q [BH][T][D]
  unsigned short* kb  = (unsigned short*)alloc((size_t)M_ * C_ * 2);  // K [BH][T][D]
  unsigned short* vtb = (unsigned short*)alloc((size_t)M_ * C_ * 2);  // V^T [BH][D][T]
  unsigned short* yb  = (unsigned short*)alloc((size_t)M_ * C_ * 2);  // attn out bf16

  cast_f32_bf16<<<dim3(M_ * C_ / 1024), dim3(256), 0, stream>>>(x, xb, M_ * C_);
  transpose_cast<<<dim3(N3 / 32, KDIM / 32), dim3(32, 8), 0, stream>>>(w_attn, wat, KDIM, N3);
  transpose_cast<<<dim3(C_ / 32, C_ / 32), dim3(32, 8), 0, stream>>>(w_proj, wpt, C_, C_);

  gemm128<0><<<dim3(N3 / 128, M_ / 128), dim3(256), 0, stream>>>(xb, wat, qb, kb, vtb, nullptr);
  attn64<<<dim3(B_ * H_, T_ / 64), dim3(256), 0, stream>>>(qb, kb, vtb, yb);
  gemm128<1><<<dim3(C_ / 128, M_ / 128), dim3(256), 0, stream>>>(yb, wpt, nullptr, nullptr, nullptr, out);
}